// Round 3
// baseline (2289.407 us; speedup 1.0000x reference)
//
#include <hip/hip_runtime.h>

// LSNN: B=64, T=1024, I=128, H=512, O=10
// d_in: x[64,1024,128], Wi[512,128], bi[512], Wr[512,512], Wo[10,512], bo[10] (f32)
// d_out: output[64,10] (640 floats) ++ hidden_states[64,1024,512] (spikes, f32)
//
// Numerics strategy: the checking reference computes the scan in f32 (proved:
// an f64-exact trajectory still flipped spikes). We therefore replicate the
// numpy-f32 reference's rounding structure bitwise:
//  - x_proj: np.einsum SSE path = 4-lane vector accumulator, UNFUSED mul+add,
//    ascending k, hsum (s0+s1)+(s2+s3), then separate +bi add.
//  - spikes@Wr: OpenBLAS sgemm = per-element ascending-k FMA chain; with 0/1
//    spikes this equals ascending adds of spiking rows; kc=384 K-blocking
//    gives rec = chain(j<384) + chain(j>=384).
//  - h = ALPHA*h + tc as two separately-rounded f32 ops (no FMA contraction;
//    empty-asm opacity barriers defeat hipcc's default -ffp-contract=fast).

#define ALPHA_F 0.951229424500714f  // rounds to f32 0.95122945308685302734 = np.float32(exp(-0.05))

__device__ float g_mean[64 * 512];  // per-(b,h) spike rate; written before read each launch

// ---------------------------------------------------------------------------
// Kernel A: x_proj[m,h] = einsum-f32(x[m,:], Wi[h,:]) + bi[h]
// M = 65536, N = 512, K = 128. Tile 64m x 32h, 256 threads, 4x2 micro-tile.
// Emulates numpy einsum's SSE 4-lane accumulation exactly.
// ---------------------------------------------------------------------------
__global__ __launch_bounds__(256) void xproj_kernel(
    const float* __restrict__ x, const float* __restrict__ Wi,
    const float* __restrict__ bi, float* __restrict__ out)
{
    __shared__ float xs[64][132];   // [m][k], padded to break bank conflicts
    __shared__ float ws[32][132];   // [h][k], padded

    const int tid = threadIdx.x;
    const int bm = blockIdx.x;   // 0..1023 (m tile)
    const int bn = blockIdx.y;   // 0..15   (h tile)

    const float* xb = x  + (size_t)bm * 64 * 128;
    const float* wb = Wi + (size_t)bn * 32 * 128;

    for (int l = 0; l < 8; ++l) {               // 2048 float4
        int idx = l * 256 + tid;
        int row = idx >> 5, c4 = idx & 31;
        *(float4*)(&xs[row][c4 * 4]) = *(const float4*)(xb + row * 128 + c4 * 4);
    }
    for (int l = 0; l < 4; ++l) {               // 1024 float4
        int idx = l * 256 + tid;
        int row = idx >> 5, c4 = idx & 31;
        *(float4*)(&ws[row][c4 * 4]) = *(const float4*)(wb + row * 128 + c4 * 4);
    }
    __syncthreads();

    const int txh = tid & 15, txm = tid >> 4;
    const int m0 = txm * 4, h0 = txh * 2;

    // acc[mm][q] = 4 SSE-lane partial sums (lane l accumulates k === l mod 4)
    float4 acc[4][2];
    #pragma unroll
    for (int mm = 0; mm < 4; ++mm)
        #pragma unroll
        for (int q = 0; q < 2; ++q)
            acc[mm][q] = make_float4(0.f, 0.f, 0.f, 0.f);

    for (int k4 = 0; k4 < 32; ++k4) {
        float4 a[4], b[2];
        #pragma unroll
        for (int mm = 0; mm < 4; ++mm) a[mm] = *(const float4*)(&xs[m0 + mm][k4 * 4]);
        #pragma unroll
        for (int q = 0; q < 2; ++q)    b[q]  = *(const float4*)(&ws[h0 + q][k4 * 4]);
        #pragma unroll
        for (int mm = 0; mm < 4; ++mm) {
            #pragma unroll
            for (int q = 0; q < 2; ++q) {
                float p0 = a[mm].x * b[q].x;
                float p1 = a[mm].y * b[q].y;
                float p2 = a[mm].z * b[q].z;
                float p3 = a[mm].w * b[q].w;
                // opacity barrier: forbid mul+add -> fma contraction
                asm volatile("" : "+v"(p0), "+v"(p1), "+v"(p2), "+v"(p3));
                acc[mm][q].x += p0;
                acc[mm][q].y += p1;
                acc[mm][q].z += p2;
                acc[mm][q].w += p3;
            }
        }
    }

    const int hbase = bn * 32 + h0;
    #pragma unroll
    for (int mm = 0; mm < 4; ++mm) {
        size_t m = (size_t)bm * 64 + m0 + mm;
        float2 o;
        {   // hsum = (s0+s1)+(s2+s3), then separate +bi (matches einsum then +bias)
            float s01 = acc[mm][0].x + acc[mm][0].y;
            float s23 = acc[mm][0].z + acc[mm][0].w;
            float hs  = s01 + s23;
            o.x = hs + bi[hbase + 0];
        }
        {
            float s01 = acc[mm][1].x + acc[mm][1].y;
            float s23 = acc[mm][1].z + acc[mm][1].w;
            float hs  = s01 + s23;
            o.y = hs + bi[hbase + 1];
        }
        *(float2*)(&out[m * 512 + hbase]) = o;
    }
}

// ---------------------------------------------------------------------------
// Kernel B: LIF scan, f32 state, numpy-faithful rounding.
// One block per batch sample, 512 threads = one neuron each.
// rec = chain(spiking j<384) + chain(spiking j>=384)   (sgemm kc=384 split)
// h   = (ALPHA*h) + (xp + rec)  with each op separately rounded.
// ---------------------------------------------------------------------------
__global__ __launch_bounds__(512) void scan_kernel(
    const float* __restrict__ Wr, float* __restrict__ hid)
{
    const int b    = blockIdx.x;
    const int h    = threadIdx.x;
    const int wv   = h >> 6;
    const int lane = h & 63;

    __shared__ unsigned short list[512];  // sorted spiking indices (prev step)
    __shared__ int wcnt[8];

    float hstate = 0.0f;
    int cnt = 0;
    int k = 0, kA = 0;                    // kA = #spiking with j < 384

    float* base = hid + (size_t)b * 1024 * 512;
    const float* wcol = Wr + h;

    for (int t = 0; t < 1024; ++t) {
        float xp = base[(size_t)t * 512 + h];   // x_proj[b,t,h]

        float recA = 0.0f, recB = 0.0f;
        int n = 0;
        for (; n + 4 <= kA; n += 4) {
            int j0 = list[n], j1 = list[n + 1], j2 = list[n + 2], j3 = list[n + 3];
            float w0 = wcol[j0 * 512], w1 = wcol[j1 * 512];
            float w2 = wcol[j2 * 512], w3 = wcol[j3 * 512];
            recA += w0; recA += w1; recA += w2; recA += w3;   // ascending chain
        }
        for (; n < kA; ++n) recA += wcol[(int)list[n] * 512];
        for (; n + 4 <= k; n += 4) {
            int j0 = list[n], j1 = list[n + 1], j2 = list[n + 2], j3 = list[n + 3];
            float w0 = wcol[j0 * 512], w1 = wcol[j1 * 512];
            float w2 = wcol[j2 * 512], w3 = wcol[j3 * 512];
            recB += w0; recB += w1; recB += w2; recB += w3;
        }
        for (; n < k; ++n) recB += wcol[(int)list[n] * 512];

        float rec = recA + recB;   // kc-block join
        float cur = xp + rec;      // cur_t + matmul result

        float tmp = ALPHA_F * hstate;
        asm volatile("" : "+v"(tmp));   // forbid fma(alpha,h,cur)
        float hn = tmp + cur;

        bool sp = (hn >= 1.0f);    // == (hn - 1.0f >= 0) exactly
        hstate = sp ? 0.0f : hn;
        base[(size_t)t * 512 + h] = sp ? 1.0f : 0.0f;
        cnt += sp ? 1 : 0;

        // build next sorted spike list (deterministic ballot/prefix compaction)
        unsigned long long m = __ballot(sp);
        int pos = __popcll(m & ((1ull << lane) - 1ull));
        __syncthreads();                    // all reads of old list done
        if (lane == 0) wcnt[wv] = __popcll(m);
        __syncthreads();                    // wcnt visible
        int off = 0, ktot = 0, ka = 0;
        #pragma unroll
        for (int w = 0; w < 8; ++w) {
            int c = wcnt[w];
            if (w < wv) off += c;
            if (w < 6)  ka  += c;           // j<384 <=> wave<6
            ktot += c;
        }
        if (sp) list[off + pos] = (unsigned short)h;
        k = ktot; kA = ka;
        __syncthreads();                    // new list visible
    }

    g_mean[b * 512 + h] = (float)cnt * (1.0f / 1024.0f);
}

// ---------------------------------------------------------------------------
// Kernel C: output[b,o] = dot(g_mean[b,:], Wo[o,:]) + bo[o], f64 accum
// (hidden_mean is exact; 2e-2 tolerance -> any accurate sum passes).
// ---------------------------------------------------------------------------
__global__ __launch_bounds__(64) void readout_kernel(
    const float* __restrict__ Wo, const float* __restrict__ bo,
    float* __restrict__ out)
{
    const int b = blockIdx.x, o = blockIdx.y;
    const int lane = threadIdx.x;
    const float* mr = g_mean + b * 512;
    const float* wr = Wo + o * 512;
    double s = 0.0;
    for (int i = lane; i < 512; i += 64) s += (double)mr[i] * (double)wr[i];
    #pragma unroll
    for (int off = 32; off; off >>= 1) s += __shfl_down(s, off);
    if (lane == 0) out[b * 10 + o] = (float)(s + (double)bo[o]);
}

extern "C" void kernel_launch(void* const* d_in, const int* in_sizes, int n_in,
                              void* d_out, int out_size, void* d_ws, size_t ws_size,
                              hipStream_t stream) {
    const float* x  = (const float*)d_in[0];
    const float* Wi = (const float*)d_in[1];
    const float* bi = (const float*)d_in[2];
    const float* Wr = (const float*)d_in[3];
    const float* Wo = (const float*)d_in[4];
    const float* bo = (const float*)d_in[5];

    float* out = (float*)d_out;
    float* hid = out + 640;  // hidden_states region doubles as x_proj scratch

    dim3 gA(1024, 16);
    xproj_kernel<<<gA, 256, 0, stream>>>(x, Wi, bi, hid);

    scan_kernel<<<64, 512, 0, stream>>>(Wr, hid);

    dim3 gC(64, 10);
    readout_kernel<<<gC, 64, 0, stream>>>(Wo, bo, out);
}

// Round 4
// 2248.847 us; speedup vs baseline: 1.0180x; 1.0180x over previous
//
#include <hip/hip_runtime.h>

// LSNN: B=64, T=1024, I=128, H=512, O=10
// d_in: x[64,1024,128], Wi[512,128], bi[512], Wr[512,512], Wo[10,512], bo[10] (f32)
// d_out: output[64,10] (640 floats) ++ hidden_states[64,1024,512] (spikes, f32)
//
// Numerics (FROZEN -- round 3 passed with absmax 0.0, bitwise):
//  - x_proj: np.einsum SSE emulation: 4-lane accumulator, UNFUSED mul+add,
//    ascending k, hsum (s0+s1)+(s2+s3), separate +bi.
//  - spikes@Wr: ascending-j add chain, split rec = chain(j<384) + chain(j>=384)
//    (OpenBLAS kc=384 K-blocking).
//  - h = (ALPHA*h) + (xp + rec), each op separately rounded (asm blocks fma).
// This round changes ONLY scheduling of the scan: deep-pipelined gather
// (depth-3 chunks of 8), saddr 32-bit addressing, 2 light barriers
// (lgkmcnt-only -- global loads/stores stay in flight across them).

#define ALPHA_F 0.951229424500714f  // np.float32(exp(-0.05))

__device__ float g_mean[64 * 512];  // written before read each launch

// ---------------------------------------------------------------------------
// Kernel A: x_proj -- UNCHANGED from round 3 (bitwise-verified).
// ---------------------------------------------------------------------------
__global__ __launch_bounds__(256) void xproj_kernel(
    const float* __restrict__ x, const float* __restrict__ Wi,
    const float* __restrict__ bi, float* __restrict__ out)
{
    __shared__ float xs[64][132];
    __shared__ float ws[32][132];

    const int tid = threadIdx.x;
    const int bm = blockIdx.x;
    const int bn = blockIdx.y;

    const float* xb = x  + (size_t)bm * 64 * 128;
    const float* wb = Wi + (size_t)bn * 32 * 128;

    for (int l = 0; l < 8; ++l) {
        int idx = l * 256 + tid;
        int row = idx >> 5, c4 = idx & 31;
        *(float4*)(&xs[row][c4 * 4]) = *(const float4*)(xb + row * 128 + c4 * 4);
    }
    for (int l = 0; l < 4; ++l) {
        int idx = l * 256 + tid;
        int row = idx >> 5, c4 = idx & 31;
        *(float4*)(&ws[row][c4 * 4]) = *(const float4*)(wb + row * 128 + c4 * 4);
    }
    __syncthreads();

    const int txh = tid & 15, txm = tid >> 4;
    const int m0 = txm * 4, h0 = txh * 2;

    float4 acc[4][2];
    #pragma unroll
    for (int mm = 0; mm < 4; ++mm)
        #pragma unroll
        for (int q = 0; q < 2; ++q)
            acc[mm][q] = make_float4(0.f, 0.f, 0.f, 0.f);

    for (int k4 = 0; k4 < 32; ++k4) {
        float4 a[4], b[2];
        #pragma unroll
        for (int mm = 0; mm < 4; ++mm) a[mm] = *(const float4*)(&xs[m0 + mm][k4 * 4]);
        #pragma unroll
        for (int q = 0; q < 2; ++q)    b[q]  = *(const float4*)(&ws[h0 + q][k4 * 4]);
        #pragma unroll
        for (int mm = 0; mm < 4; ++mm) {
            #pragma unroll
            for (int q = 0; q < 2; ++q) {
                float p0 = a[mm].x * b[q].x;
                float p1 = a[mm].y * b[q].y;
                float p2 = a[mm].z * b[q].z;
                float p3 = a[mm].w * b[q].w;
                asm volatile("" : "+v"(p0), "+v"(p1), "+v"(p2), "+v"(p3));
                acc[mm][q].x += p0;
                acc[mm][q].y += p1;
                acc[mm][q].z += p2;
                acc[mm][q].w += p3;
            }
        }
    }

    const int hbase = bn * 32 + h0;
    #pragma unroll
    for (int mm = 0; mm < 4; ++mm) {
        size_t m = (size_t)bm * 64 + m0 + mm;
        float2 o;
        {
            float s01 = acc[mm][0].x + acc[mm][0].y;
            float s23 = acc[mm][0].z + acc[mm][0].w;
            float hs  = s01 + s23;
            o.x = hs + bi[hbase + 0];
        }
        {
            float s01 = acc[mm][1].x + acc[mm][1].y;
            float s23 = acc[mm][1].z + acc[mm][1].w;
            float hs  = s01 + s23;
            o.y = hs + bi[hbase + 1];
        }
        *(float2*)(&out[m * 512 + hbase]) = o;
    }
}

// ---------------------------------------------------------------------------
// Kernel B: LIF scan, deep-pipelined gather.
// ---------------------------------------------------------------------------
struct C8 { float a, b, c, d, e, f, g, h; };

__device__ __forceinline__ C8 fetch8(const unsigned short* lst, int c,
                                     const float* __restrict__ Wr, unsigned hh) {
    const uint4* lv = (const uint4*)lst;
    uint4 L = lv[c];
    unsigned o0 = ((L.x & 0xffffu) << 9) + hh;
    unsigned o1 = ((L.x >> 16)     << 9) + hh;
    unsigned o2 = ((L.y & 0xffffu) << 9) + hh;
    unsigned o3 = ((L.y >> 16)     << 9) + hh;
    unsigned o4 = ((L.z & 0xffffu) << 9) + hh;
    unsigned o5 = ((L.z >> 16)     << 9) + hh;
    unsigned o6 = ((L.w & 0xffffu) << 9) + hh;
    unsigned o7 = ((L.w >> 16)     << 9) + hh;
    C8 r;
    r.a = Wr[o0]; r.b = Wr[o1]; r.c = Wr[o2]; r.d = Wr[o3];
    r.e = Wr[o4]; r.f = Wr[o5]; r.g = Wr[o6]; r.h = Wr[o7];
    return r;
}

// consume entries [e, e+8) in ascending order; split chains at kA (uniform).
__device__ __forceinline__ void consume8(const C8& v, int e, int kA, int k,
                                         float& recA, float& recB) {
    if (e + 8 <= kA) {
        recA += v.a; recA += v.b; recA += v.c; recA += v.d;
        recA += v.e; recA += v.f; recA += v.g; recA += v.h;
    } else if (e >= kA && e + 8 <= k) {
        recB += v.a; recB += v.b; recB += v.c; recB += v.d;
        recB += v.e; recB += v.f; recB += v.g; recB += v.h;
    } else {
        if (e + 0 < k) { if (e + 0 < kA) recA += v.a; else recB += v.a; }
        if (e + 1 < k) { if (e + 1 < kA) recA += v.b; else recB += v.b; }
        if (e + 2 < k) { if (e + 2 < kA) recA += v.c; else recB += v.c; }
        if (e + 3 < k) { if (e + 3 < kA) recA += v.d; else recB += v.d; }
        if (e + 4 < k) { if (e + 4 < kA) recA += v.e; else recB += v.e; }
        if (e + 5 < k) { if (e + 5 < kA) recA += v.f; else recB += v.f; }
        if (e + 6 < k) { if (e + 6 < kA) recA += v.g; else recB += v.g; }
        if (e + 7 < k) { if (e + 7 < kA) recA += v.h; else recB += v.h; }
    }
}

// light barrier: order LDS only; global loads/stores stay in flight.
#define BAR() do { \
    asm volatile("s_waitcnt lgkmcnt(0)" ::: "memory"); \
    __builtin_amdgcn_s_barrier(); \
    asm volatile("" ::: "memory"); \
} while (0)

__global__ __launch_bounds__(512, 1) void scan_kernel(
    const float* __restrict__ Wr, float* __restrict__ hid)
{
    const int b    = blockIdx.x;
    const int h    = threadIdx.x;
    const int wv   = h >> 6;
    const int lane = h & 63;
    const unsigned hh = (unsigned)h;

    __shared__ alignas(16) unsigned short list[512];
    __shared__ alignas(16) int wcnt[8];

    list[h] = 0;          // bound tail-garbage indices (<=511)
    __syncthreads();

    const int wvs = __builtin_amdgcn_readfirstlane(wv);

    float hstate = 0.0f;
    int cnt = 0;
    int k = 0, kA = 0;

    float* base = hid + (size_t)b * 1024 * 512;
    float xp = base[h];   // x_proj[b,0,h]
    const unsigned long long lmask = (1ull << lane) - 1ull;

    for (int t = 0; t < 1024; ++t) {
        // prefetch next step's x_proj early (hidden under the gather)
        int tn = (t < 1023) ? t + 1 : 1023;
        float xp_next = base[(size_t)tn * 512 + h];

        float recA = 0.0f, recB = 0.0f;
        int nch = (k + 7) >> 3;

        C8 b0, b1, b2;
        if (nch > 0) b0 = fetch8(list, 0, Wr, hh);
        if (nch > 1) b1 = fetch8(list, 1, Wr, hh);
        if (nch > 2) b2 = fetch8(list, 2, Wr, hh);
        int c = 0;
        for (; c + 6 <= nch; c += 3) {
            consume8(b0, (c + 0) * 8, kA, k, recA, recB); b0 = fetch8(list, c + 3, Wr, hh);
            consume8(b1, (c + 1) * 8, kA, k, recA, recB); b1 = fetch8(list, c + 4, Wr, hh);
            consume8(b2, (c + 2) * 8, kA, k, recA, recB); b2 = fetch8(list, c + 5, Wr, hh);
        }
        int rem = nch - c;   // 0..5
        if (rem >= 1) consume8(b0, (c + 0) * 8, kA, k, recA, recB);
        if (rem >= 4) b0 = fetch8(list, c + 3, Wr, hh);
        if (rem >= 2) consume8(b1, (c + 1) * 8, kA, k, recA, recB);
        if (rem >= 5) b1 = fetch8(list, c + 4, Wr, hh);
        if (rem >= 3) consume8(b2, (c + 2) * 8, kA, k, recA, recB);
        if (rem >= 4) consume8(b0, (c + 3) * 8, kA, k, recA, recB);
        if (rem >= 5) consume8(b1, (c + 4) * 8, kA, k, recA, recB);

        // state update (FROZEN semantics)
        float rec = recA + recB;        // kc-block join
        float cur = xp + rec;
        float tmp = ALPHA_F * hstate;
        asm volatile("" : "+v"(tmp));   // forbid fma contraction
        float hn = tmp + cur;
        bool sp = (hn >= 1.0f);
        hstate = sp ? 0.0f : hn;
        base[(size_t)t * 512 + h] = sp ? 1.0f : 0.0f;
        cnt += sp ? 1 : 0;

        unsigned long long m = __ballot(sp);
        int pos = __popcll(m & lmask);
        if (lane == 0) wcnt[wv] = __popcll(m);

        BAR();  // #1: wcnt visible; all list reads of this step complete

        int4 wa = *(const int4*)&wcnt[0];
        int4 wb = *(const int4*)&wcnt[4];
        int off = 0;
        if (wvs > 0) off += wa.x;
        if (wvs > 1) off += wa.y;
        if (wvs > 2) off += wa.z;
        if (wvs > 3) off += wa.w;
        if (wvs > 4) off += wb.x;
        if (wvs > 5) off += wb.y;
        if (wvs > 6) off += wb.z;
        int nkA = wa.x + wa.y + wa.z + wa.w + wb.x + wb.y;  // j<384 <=> wave<6
        int nk  = nkA + wb.z + wb.w;
        if (sp) list[off + pos] = (unsigned short)h;

        BAR();  // #2: new list visible for next step

        k  = __builtin_amdgcn_readfirstlane(nk);
        kA = __builtin_amdgcn_readfirstlane(nkA);
        xp = xp_next;
    }

    g_mean[b * 512 + h] = (float)cnt * (1.0f / 1024.0f);
}

// ---------------------------------------------------------------------------
// Kernel C: readout -- UNCHANGED from round 3.
// ---------------------------------------------------------------------------
__global__ __launch_bounds__(64) void readout_kernel(
    const float* __restrict__ Wo, const float* __restrict__ bo,
    float* __restrict__ out)
{
    const int b = blockIdx.x, o = blockIdx.y;
    const int lane = threadIdx.x;
    const float* mr = g_mean + b * 512;
    const float* wr = Wo + o * 512;
    double s = 0.0;
    for (int i = lane; i < 512; i += 64) s += (double)mr[i] * (double)wr[i];
    #pragma unroll
    for (int off = 32; off; off >>= 1) s += __shfl_down(s, off);
    if (lane == 0) out[b * 10 + o] = (float)(s + (double)bo[o]);
}

extern "C" void kernel_launch(void* const* d_in, const int* in_sizes, int n_in,
                              void* d_out, int out_size, void* d_ws, size_t ws_size,
                              hipStream_t stream) {
    const float* x  = (const float*)d_in[0];
    const float* Wi = (const float*)d_in[1];
    const float* bi = (const float*)d_in[2];
    const float* Wr = (const float*)d_in[3];
    const float* Wo = (const float*)d_in[4];
    const float* bo = (const float*)d_in[5];

    float* out = (float*)d_out;
    float* hid = out + 640;  // hidden_states region doubles as x_proj scratch

    dim3 gA(1024, 16);
    xproj_kernel<<<gA, 256, 0, stream>>>(x, Wi, bi, hid);

    scan_kernel<<<64, 512, 0, stream>>>(Wr, hid);

    dim3 gC(64, 10);
    readout_kernel<<<gC, 64, 0, stream>>>(Wo, bo, out);
}

// Round 6
// 2131.685 us; speedup vs baseline: 1.0740x; 1.0550x over previous
//
#include <hip/hip_runtime.h>

// LSNN: B=64, T=1024, I=128, H=512, O=10
// d_in: x[64,1024,128], Wi[512,128], bi[512], Wr[512,512], Wo[10,512], bo[10] (f32)
// d_out: output[64,10] (640 floats) ++ hidden_states[64,1024,512] (spikes, f32)
//
// Numerics (FROZEN -- rounds 3/4 passed with absmax 0.0, bitwise):
//  - x_proj: np.einsum SSE emulation (4-lane acc, unfused mul+add, hsum, +bi).
//  - spikes@Wr: ascending-j add chain, rec = chain(j<384) + chain(j>=384).
//  - h = (ALPHA*h) + (xp + rec), each op separately rounded.
//
// Scan decomposition: 256 blocks = 8 column-slices x 32 sample-pairs; Wr slice
// [512][64] in LDS (128KB, 1 block/CU); per-step 512-bit spike masks exchanged
// through d_ws as 16B {mask_lo, mask_hi, seq, pad} records, published/polled
// with single-transaction dwordx4 sc0 sc1 (device-coherent). Slices of one
// sample stay on one XCD (blk%8 == p%8).

#define ALPHA_F 0.951229424500714f  // np.float32(exp(-0.05))

typedef unsigned int u32x4 __attribute__((ext_vector_type(4)));  // direct VGPR quad for asm

__device__ float g_mean[64 * 512];  // written before read each launch

// ---------------------------------------------------------------------------
// Kernel A: x_proj -- UNCHANGED (bitwise-verified).
// ---------------------------------------------------------------------------
__global__ __launch_bounds__(256) void xproj_kernel(
    const float* __restrict__ x, const float* __restrict__ Wi,
    const float* __restrict__ bi, float* __restrict__ out)
{
    __shared__ float xs[64][132];
    __shared__ float ws[32][132];

    const int tid = threadIdx.x;
    const int bm = blockIdx.x;
    const int bn = blockIdx.y;

    const float* xb = x  + (size_t)bm * 64 * 128;
    const float* wb = Wi + (size_t)bn * 32 * 128;

    for (int l = 0; l < 8; ++l) {
        int idx = l * 256 + tid;
        int row = idx >> 5, c4 = idx & 31;
        *(float4*)(&xs[row][c4 * 4]) = *(const float4*)(xb + row * 128 + c4 * 4);
    }
    for (int l = 0; l < 4; ++l) {
        int idx = l * 256 + tid;
        int row = idx >> 5, c4 = idx & 31;
        *(float4*)(&ws[row][c4 * 4]) = *(const float4*)(wb + row * 128 + c4 * 4);
    }
    __syncthreads();

    const int txh = tid & 15, txm = tid >> 4;
    const int m0 = txm * 4, h0 = txh * 2;

    float4 acc[4][2];
    #pragma unroll
    for (int mm = 0; mm < 4; ++mm)
        #pragma unroll
        for (int q = 0; q < 2; ++q)
            acc[mm][q] = make_float4(0.f, 0.f, 0.f, 0.f);

    for (int k4 = 0; k4 < 32; ++k4) {
        float4 a[4], b[2];
        #pragma unroll
        for (int mm = 0; mm < 4; ++mm) a[mm] = *(const float4*)(&xs[m0 + mm][k4 * 4]);
        #pragma unroll
        for (int q = 0; q < 2; ++q)    b[q]  = *(const float4*)(&ws[h0 + q][k4 * 4]);
        #pragma unroll
        for (int mm = 0; mm < 4; ++mm) {
            #pragma unroll
            for (int q = 0; q < 2; ++q) {
                float p0 = a[mm].x * b[q].x;
                float p1 = a[mm].y * b[q].y;
                float p2 = a[mm].z * b[q].z;
                float p3 = a[mm].w * b[q].w;
                asm volatile("" : "+v"(p0), "+v"(p1), "+v"(p2), "+v"(p3));
                acc[mm][q].x += p0;
                acc[mm][q].y += p1;
                acc[mm][q].z += p2;
                acc[mm][q].w += p3;
            }
        }
    }

    const int hbase = bn * 32 + h0;
    #pragma unroll
    for (int mm = 0; mm < 4; ++mm) {
        size_t m = (size_t)bm * 64 + m0 + mm;
        float2 o;
        {
            float s01 = acc[mm][0].x + acc[mm][0].y;
            float s23 = acc[mm][0].z + acc[mm][0].w;
            float hs  = s01 + s23;
            o.x = hs + bi[hbase + 0];
        }
        {
            float s01 = acc[mm][1].x + acc[mm][1].y;
            float s23 = acc[mm][1].z + acc[mm][1].w;
            float hs  = s01 + s23;
            o.y = hs + bi[hbase + 1];
        }
        *(float2*)(&out[m * 512 + hbase]) = o;
    }
}

// ---------------------------------------------------------------------------
// Kernel B: LIF scan, 8 slice-blocks per sample, Wr slice in LDS.
// ---------------------------------------------------------------------------
struct C8 { float a, b, c, d, e, f, g, h; };

__device__ __forceinline__ C8 fetch8_lds(const unsigned short* lst, int cidx,
                                         const float (*wrs)[64], int lane) {
    uint4 L = ((const uint4*)lst)[cidx];   // 8 entries, wave-uniform broadcast
    int j0 = (int)(L.x & 0xffffu), j1 = (int)(L.x >> 16);
    int j2 = (int)(L.y & 0xffffu), j3 = (int)(L.y >> 16);
    int j4 = (int)(L.z & 0xffffu), j5 = (int)(L.z >> 16);
    int j6 = (int)(L.w & 0xffffu), j7 = (int)(L.w >> 16);
    C8 r;
    r.a = wrs[j0][lane]; r.b = wrs[j1][lane];
    r.c = wrs[j2][lane]; r.d = wrs[j3][lane];
    r.e = wrs[j4][lane]; r.f = wrs[j5][lane];
    r.g = wrs[j6][lane]; r.h = wrs[j7][lane];
    return r;
}

// consume entries [e, e+8) ascending; split chains at kA (uniform). FROZEN.
__device__ __forceinline__ void consume8(const C8& v, int e, int kA, int k,
                                         float& recA, float& recB) {
    if (e + 8 <= kA) {
        recA += v.a; recA += v.b; recA += v.c; recA += v.d;
        recA += v.e; recA += v.f; recA += v.g; recA += v.h;
    } else if (e >= kA && e + 8 <= k) {
        recB += v.a; recB += v.b; recB += v.c; recB += v.d;
        recB += v.e; recB += v.f; recB += v.g; recB += v.h;
    } else {
        if (e + 0 < k) { if (e + 0 < kA) recA += v.a; else recB += v.a; }
        if (e + 1 < k) { if (e + 1 < kA) recA += v.b; else recB += v.b; }
        if (e + 2 < k) { if (e + 2 < kA) recA += v.c; else recB += v.c; }
        if (e + 3 < k) { if (e + 3 < kA) recA += v.d; else recB += v.d; }
        if (e + 4 < k) { if (e + 4 < kA) recA += v.e; else recB += v.e; }
        if (e + 5 < k) { if (e + 5 < kA) recA += v.f; else recB += v.f; }
        if (e + 6 < k) { if (e + 6 < kA) recA += v.g; else recB += v.g; }
        if (e + 7 < k) { if (e + 7 < kA) recA += v.h; else recB += v.h; }
    }
}

__global__ __launch_bounds__(128, 1) void scan_kernel(
    const float* __restrict__ Wr, float* __restrict__ hid,
    u32x4* __restrict__ syn)
{
    const int blk  = blockIdx.x;    // 0..255
    const int p    = blk & 31;      // sample pair (slices of a pair share an XCD)
    const int c    = blk >> 5;      // column slice 0..7
    const int tid  = threadIdx.x;   // 0..127
    const int w    = tid >> 6;      // wave -> sample select
    const int lane = tid & 63;
    const int s    = p + 32 * w;    // sample
    const int n    = (c << 6) + lane;

    __shared__ float wrs[512][64];            // Wr[:, c*64 .. c*64+64) : 128 KB
    __shared__ unsigned short lists[2][512];  // per-wave spike index list

    #pragma unroll
    for (int i = 0; i < 8; ++i) ((unsigned short*)lists)[tid * 8 + i] = 0;

    {   // load Wr slice into LDS (coalesced 256B row segments)
        const float* src = Wr + (c << 6);
        for (int it = 0; it < 64; ++it) {
            int idx = it * 128 + tid;      // 0..8191 float4s
            int r = idx >> 4, q = idx & 15;
            float4 v = *(const float4*)(src + (size_t)r * 512 + q * 4);
            *(float4*)(&wrs[r][q * 4]) = v;
        }
    }
    __syncthreads();   // only barrier; waves are independent afterwards

    unsigned short* list = lists[w];
    float* base = hid + ((size_t)s * 1024) * 512 + n;

    float hstate = 0.0f;
    int cnt = 0;
    float xp = base[0];

    for (int t = 0; t < 1024; ++t) {
        float xp_next = base[(size_t)(t < 1023 ? t + 1 : 1023) * 512];

        int k = 0, kA = 0;
        if (t > 0) {
            // poll partner masks(t-1): 16B {mask_lo, mask_hi, seq, pad} per slice
            const u32x4* pp = syn + ((((t - 1) & 1) * 64 + s) * 8) + (lane & 7);
            u32x4 pv;
            for (;;) {
                u32x4 tv;
                asm volatile("global_load_dwordx4 %0, %1, off sc0 sc1\n\t"
                             "s_waitcnt vmcnt(0)"
                             : "=v"(tv) : "v"(pp) : "memory");
                unsigned long long ok = __ballot(tv.z == (unsigned)t);
                if ((ok & 0xFFull) == 0xFFull) { pv = tv; break; }
                __builtin_amdgcn_s_sleep(1);
            }
            // build ascending-j list: lane L owns bits [L*8, L*8+8) of the 512-bit mask
            unsigned long long fullm = (((unsigned long long)pv.y) << 32) | pv.x;
            int pc = __popcll(fullm);            // popcount of slice (lane&7)
            int sc_ = pc, u_;
            u_ = __shfl_up(sc_, 1); if (lane >= 1) sc_ += u_;
            u_ = __shfl_up(sc_, 2); if (lane >= 2) sc_ += u_;
            u_ = __shfl_up(sc_, 4); if (lane >= 4) sc_ += u_;   // incl prefix (lanes 0..7)
            int excl = sc_ - pc;
            k  = __builtin_amdgcn_readfirstlane(__shfl(sc_, 7));
            kA = __builtin_amdgcn_readfirstlane(__shfl(sc_, 5));  // j<384 <=> slices 0..5
            unsigned mlo = (unsigned)__shfl((int)pv.x, lane >> 3);
            unsigned mhi = (unsigned)__shfl((int)pv.y, lane >> 3);
            int ep = __shfl(excl, lane >> 3);
            int sb = (lane & 7) * 8;
            unsigned byte; int below;
            if (sb < 32) {
                byte  = (mlo >> sb) & 0xFFu;
                below = __popc(mlo & ((1u << sb) - 1u));
            } else {
                byte  = (mhi >> (sb - 32)) & 0xFFu;
                below = __popc(mlo) + __popc(mhi & ((1u << (sb - 32)) - 1u));
            }
            int pos = ep + below;
            while (byte) {
                int bt = __builtin_ctz(byte);
                byte &= byte - 1;
                list[pos++] = (unsigned short)(lane * 8 + bt);  // j = lane*8 + bt
            }
        }

        float recA = 0.0f, recB = 0.0f;
        if (k > 0) {
            int nch = (k + 7) >> 3;
            C8 b0, b1;
            b0 = fetch8_lds(list, 0, wrs, lane);
            if (nch > 1) b1 = fetch8_lds(list, 1, wrs, lane);
            int cc = 0;
            for (; cc + 4 <= nch; cc += 2) {
                consume8(b0, (cc + 0) * 8, kA, k, recA, recB);
                b0 = fetch8_lds(list, cc + 2, wrs, lane);
                consume8(b1, (cc + 1) * 8, kA, k, recA, recB);
                b1 = fetch8_lds(list, cc + 3, wrs, lane);
            }
            int rem = nch - cc;   // 1..3
            if (rem >= 1) consume8(b0, (cc + 0) * 8, kA, k, recA, recB);
            if (rem >= 3) b0 = fetch8_lds(list, cc + 2, wrs, lane);
            if (rem >= 2) consume8(b1, (cc + 1) * 8, kA, k, recA, recB);
            if (rem >= 3) consume8(b0, (cc + 2) * 8, kA, k, recA, recB);
        }

        // state update (FROZEN semantics)
        float rec = recA + recB;        // kc-block join
        float cur = xp + rec;
        float tmp = ALPHA_F * hstate;
        asm volatile("" : "+v"(tmp));   // forbid fma contraction
        float hn = tmp + cur;
        bool sp = (hn >= 1.0f);
        hstate = sp ? 0.0f : hn;

        // publish own 64-bit mask FIRST (single 16B device-coherent store)
        unsigned long long bm = __ballot(sp);
        if (lane == 0) {
            u32x4 pk;
            pk.x = (unsigned)bm; pk.y = (unsigned)(bm >> 32);
            pk.z = (unsigned)(t + 1); pk.w = 0u;
            u32x4* qp = syn + (((t & 1) * 64 + s) * 8) + c;
            asm volatile("global_store_dwordx4 %0, %1, off sc0 sc1"
                         :: "v"(qp), "v"(pk) : "memory");
        }

        base[(size_t)t * 512] = sp ? 1.0f : 0.0f;
        cnt += sp ? 1 : 0;
        xp = xp_next;
    }

    g_mean[s * 512 + n] = (float)cnt * (1.0f / 1024.0f);
}

// ---------------------------------------------------------------------------
// Kernel C: readout -- UNCHANGED.
// ---------------------------------------------------------------------------
__global__ __launch_bounds__(64) void readout_kernel(
    const float* __restrict__ Wo, const float* __restrict__ bo,
    float* __restrict__ out)
{
    const int b = blockIdx.x, o = blockIdx.y;
    const int lane = threadIdx.x;
    const float* mr = g_mean + b * 512;
    const float* wr = Wo + o * 512;
    double s = 0.0;
    for (int i = lane; i < 512; i += 64) s += (double)mr[i] * (double)wr[i];
    #pragma unroll
    for (int off = 32; off; off >>= 1) s += __shfl_down(s, off);
    if (lane == 0) out[b * 10 + o] = (float)(s + (double)bo[o]);
}

extern "C" void kernel_launch(void* const* d_in, const int* in_sizes, int n_in,
                              void* d_out, int out_size, void* d_ws, size_t ws_size,
                              hipStream_t stream) {
    const float* x  = (const float*)d_in[0];
    const float* Wi = (const float*)d_in[1];
    const float* bi = (const float*)d_in[2];
    const float* Wr = (const float*)d_in[3];
    const float* Wo = (const float*)d_in[4];
    const float* bo = (const float*)d_in[5];

    float* out = (float*)d_out;
    float* hid = out + 640;  // hidden_states region doubles as x_proj scratch

    // zero the mask-exchange records (2 slots x 64 samples x 8 slices x 16B)
    (void)hipMemsetAsync(d_ws, 0, 2 * 64 * 8 * 16, stream);

    dim3 gA(1024, 16);
    xproj_kernel<<<gA, 256, 0, stream>>>(x, Wi, bi, hid);

    scan_kernel<<<256, 128, 0, stream>>>(Wr, hid, (u32x4*)d_ws);

    dim3 gC(64, 10);
    readout_kernel<<<gC, 64, 0, stream>>>(Wo, bo, out);
}

// Round 8
// 2084.341 us; speedup vs baseline: 1.0984x; 1.0227x over previous
//
#include <hip/hip_runtime.h>

// LSNN: B=64, T=1024, I=128, H=512, O=10
// d_in: x[64,1024,128], Wi[512,128], bi[512], Wr[512,512], Wo[10,512], bo[10] (f32)
// d_out: output[64,10] (640 floats) ++ hidden_states[64,1024,512] (spikes, f32)
//
// Numerics (FROZEN -- rounds 3/4/6 passed with absmax 0.0, bitwise):
//  - x_proj: np.einsum SSE emulation (4-lane acc, unfused mul+add, hsum, +bi).
//  - spikes@Wr: ascending-j add chain, rec = chain(j<384) + chain(j>=384).
//  - h = (ALPHA*h) + (xp + rec), each op separately rounded.
//
// Scan: 256 blocks = 8 column-slices x 32 sample-pairs; Wr slice [512][64] in
// LDS; per-step 512-bit spike masks via d_ws {mask,seq} records (sc0 sc1).
// THIS ROUND: fix round-7's in-flight-probe register-liveness hazard.
// Probe issues use "+v" (read-write) constraints so prb0/prb1 stay allocated
// across the whole loop; a stray in-flight probe can then only write its own
// pinned registers (harmless), never a reallocated live value. Post-loop
// drain + keep-alive covers the final stray. Poll structure otherwise as r7.

#define ALPHA_F 0.951229424500714f  // np.float32(exp(-0.05))

typedef unsigned int u32x4 __attribute__((ext_vector_type(4)));  // direct VGPR quad for asm

__device__ float g_mean[64 * 512];  // written before read each launch

// ---------------------------------------------------------------------------
// Kernel A: x_proj -- UNCHANGED (bitwise-verified).
// ---------------------------------------------------------------------------
__global__ __launch_bounds__(256) void xproj_kernel(
    const float* __restrict__ x, const float* __restrict__ Wi,
    const float* __restrict__ bi, float* __restrict__ out)
{
    __shared__ float xs[64][132];
    __shared__ float ws[32][132];

    const int tid = threadIdx.x;
    const int bm = blockIdx.x;
    const int bn = blockIdx.y;

    const float* xb = x  + (size_t)bm * 64 * 128;
    const float* wb = Wi + (size_t)bn * 32 * 128;

    for (int l = 0; l < 8; ++l) {
        int idx = l * 256 + tid;
        int row = idx >> 5, c4 = idx & 31;
        *(float4*)(&xs[row][c4 * 4]) = *(const float4*)(xb + row * 128 + c4 * 4);
    }
    for (int l = 0; l < 4; ++l) {
        int idx = l * 256 + tid;
        int row = idx >> 5, c4 = idx & 31;
        *(float4*)(&ws[row][c4 * 4]) = *(const float4*)(wb + row * 128 + c4 * 4);
    }
    __syncthreads();

    const int txh = tid & 15, txm = tid >> 4;
    const int m0 = txm * 4, h0 = txh * 2;

    float4 acc[4][2];
    #pragma unroll
    for (int mm = 0; mm < 4; ++mm)
        #pragma unroll
        for (int q = 0; q < 2; ++q)
            acc[mm][q] = make_float4(0.f, 0.f, 0.f, 0.f);

    for (int k4 = 0; k4 < 32; ++k4) {
        float4 a[4], b[2];
        #pragma unroll
        for (int mm = 0; mm < 4; ++mm) a[mm] = *(const float4*)(&xs[m0 + mm][k4 * 4]);
        #pragma unroll
        for (int q = 0; q < 2; ++q)    b[q]  = *(const float4*)(&ws[h0 + q][k4 * 4]);
        #pragma unroll
        for (int mm = 0; mm < 4; ++mm) {
            #pragma unroll
            for (int q = 0; q < 2; ++q) {
                float p0 = a[mm].x * b[q].x;
                float p1 = a[mm].y * b[q].y;
                float p2 = a[mm].z * b[q].z;
                float p3 = a[mm].w * b[q].w;
                asm volatile("" : "+v"(p0), "+v"(p1), "+v"(p2), "+v"(p3));
                acc[mm][q].x += p0;
                acc[mm][q].y += p1;
                acc[mm][q].z += p2;
                acc[mm][q].w += p3;
            }
        }
    }

    const int hbase = bn * 32 + h0;
    #pragma unroll
    for (int mm = 0; mm < 4; ++mm) {
        size_t m = (size_t)bm * 64 + m0 + mm;
        float2 o;
        {
            float s01 = acc[mm][0].x + acc[mm][0].y;
            float s23 = acc[mm][0].z + acc[mm][0].w;
            float hs  = s01 + s23;
            o.x = hs + bi[hbase + 0];
        }
        {
            float s01 = acc[mm][1].x + acc[mm][1].y;
            float s23 = acc[mm][1].z + acc[mm][1].w;
            float hs  = s01 + s23;
            o.y = hs + bi[hbase + 1];
        }
        *(float2*)(&out[m * 512 + hbase]) = o;
    }
}

// ---------------------------------------------------------------------------
// Kernel B: LIF scan, 8 slice-blocks per sample, Wr slice in LDS.
// ---------------------------------------------------------------------------
struct C8 { float a, b, c, d, e, f, g, h; };

__device__ __forceinline__ C8 fetch8_lds(const unsigned short* lst, int cidx,
                                         const float (*wrs)[64], int lane) {
    uint4 L = ((const uint4*)lst)[cidx];   // 8 entries, wave-uniform broadcast
    int j0 = (int)(L.x & 0xffffu), j1 = (int)(L.x >> 16);
    int j2 = (int)(L.y & 0xffffu), j3 = (int)(L.y >> 16);
    int j4 = (int)(L.z & 0xffffu), j5 = (int)(L.z >> 16);
    int j6 = (int)(L.w & 0xffffu), j7 = (int)(L.w >> 16);
    C8 r;
    r.a = wrs[j0][lane]; r.b = wrs[j1][lane];
    r.c = wrs[j2][lane]; r.d = wrs[j3][lane];
    r.e = wrs[j4][lane]; r.f = wrs[j5][lane];
    r.g = wrs[j6][lane]; r.h = wrs[j7][lane];
    return r;
}

// consume entries [e, e+8) ascending; split chains at kA (uniform). FROZEN.
__device__ __forceinline__ void consume8(const C8& v, int e, int kA, int k,
                                         float& recA, float& recB) {
    if (e + 8 <= kA) {
        recA += v.a; recA += v.b; recA += v.c; recA += v.d;
        recA += v.e; recA += v.f; recA += v.g; recA += v.h;
    } else if (e >= kA && e + 8 <= k) {
        recB += v.a; recB += v.b; recB += v.c; recB += v.d;
        recB += v.e; recB += v.f; recB += v.g; recB += v.h;
    } else {
        if (e + 0 < k) { if (e + 0 < kA) recA += v.a; else recB += v.a; }
        if (e + 1 < k) { if (e + 1 < kA) recA += v.b; else recB += v.b; }
        if (e + 2 < k) { if (e + 2 < kA) recA += v.c; else recB += v.c; }
        if (e + 3 < k) { if (e + 3 < kA) recA += v.d; else recB += v.d; }
        if (e + 4 < k) { if (e + 4 < kA) recA += v.e; else recB += v.e; }
        if (e + 5 < k) { if (e + 5 < kA) recA += v.f; else recB += v.f; }
        if (e + 6 < k) { if (e + 6 < kA) recA += v.g; else recB += v.g; }
        if (e + 7 < k) { if (e + 7 < kA) recA += v.h; else recB += v.h; }
    }
}

__global__ __launch_bounds__(128, 1) void scan_kernel(
    const float* __restrict__ Wr, float* __restrict__ hid,
    u32x4* __restrict__ syn)
{
    const int blk  = blockIdx.x;    // 0..255
    const int p    = blk & 31;      // sample pair (slices of a pair share an XCD)
    const int c    = blk >> 5;      // column slice 0..7
    const int tid  = threadIdx.x;   // 0..127
    const int w    = tid >> 6;      // wave -> sample select
    const int lane = tid & 63;
    const int s    = p + 32 * w;    // sample
    const int n    = (c << 6) + lane;

    __shared__ float wrs[512][64];            // Wr[:, c*64 .. c*64+64) : 128 KB
    __shared__ alignas(16) unsigned short lists[2][512];  // per-wave spike index list

    #pragma unroll
    for (int i = 0; i < 8; ++i) ((unsigned short*)lists)[tid * 8 + i] = 0;

    {   // load Wr slice into LDS (coalesced 256B row segments)
        const float* src = Wr + (c << 6);
        for (int it = 0; it < 64; ++it) {
            int idx = it * 128 + tid;      // 0..8191 float4s
            int r = idx >> 4, q = idx & 15;
            float4 v = *(const float4*)(src + (size_t)r * 512 + q * 4);
            *(float4*)(&wrs[r][q * 4]) = v;
        }
    }
    __syncthreads();   // only barrier; waves are independent afterwards

    unsigned short* list = lists[w];
    float* base = hid + ((size_t)s * 1024) * 512 + n;

    float hstate = 0.0f;
    int cnt = 0;
    float xp = base[0];

    // Probe quads: "+v" issue constraints below keep these registers LIVE for
    // the whole loop, so an in-flight probe can only ever write its own pinned
    // registers -- never VGPRs the allocator handed to other values.
    u32x4 prb0 = {0, 0, 0, 0}, prb1 = {0, 0, 0, 0};

    for (int t = 0; t < 1024; ++t) {
        int k = 0, kA = 0;
        if (t > 0) {
            const u32x4* pp = syn + ((((t - 1) & 1) * 64 + s) * 8) + (lane & 7);
            // pre-drain: retire prev stores + any stray in-flight probe, so
            // vmcnt below counts ONLY our probes.
            asm volatile("s_waitcnt vmcnt(0)" ::: "memory");
            u32x4 pv;
            asm volatile("global_load_dwordx4 %0, %2, off sc0 sc1\n\t"
                         "global_load_dwordx4 %1, %2, off sc0 sc1"
                         : "+v"(prb0), "+v"(prb1) : "v"(pp) : "memory");
            for (;;) {
                asm volatile("s_waitcnt vmcnt(1)" : "+v"(prb0) :: "memory");
                unsigned long long ok = __ballot(prb0.z == (unsigned)t);
                if ((ok & 0xFFull) == 0xFFull) { pv = prb0; break; }
                asm volatile("global_load_dwordx4 %0, %1, off sc0 sc1"
                             : "+v"(prb0) : "v"(pp) : "memory");
                asm volatile("s_waitcnt vmcnt(1)" : "+v"(prb1) :: "memory");
                ok = __ballot(prb1.z == (unsigned)t);
                if ((ok & 0xFFull) == 0xFFull) { pv = prb1; break; }
                asm volatile("global_load_dwordx4 %0, %1, off sc0 sc1"
                             : "+v"(prb1) : "v"(pp) : "memory");
            }
            // build ascending-j list: lane L owns bits [L*8, L*8+8) of the 512-bit mask
            unsigned long long fullm = (((unsigned long long)pv.y) << 32) | pv.x;
            int pc = __popcll(fullm);            // popcount of slice (lane&7)
            int sc_ = pc, u_;
            u_ = __shfl_up(sc_, 1); if (lane >= 1) sc_ += u_;
            u_ = __shfl_up(sc_, 2); if (lane >= 2) sc_ += u_;
            u_ = __shfl_up(sc_, 4); if (lane >= 4) sc_ += u_;   // incl prefix (lanes 0..7)
            int excl = sc_ - pc;
            k  = __builtin_amdgcn_readfirstlane(__shfl(sc_, 7));
            kA = __builtin_amdgcn_readfirstlane(__shfl(sc_, 5));  // j<384 <=> slices 0..5
            unsigned mlo = (unsigned)__shfl((int)pv.x, lane >> 3);
            unsigned mhi = (unsigned)__shfl((int)pv.y, lane >> 3);
            int ep = __shfl(excl, lane >> 3);
            int sb = (lane & 7) * 8;
            unsigned byte; int below;
            if (sb < 32) {
                byte  = (mlo >> sb) & 0xFFu;
                below = __popc(mlo & ((1u << sb) - 1u));
            } else {
                byte  = (mhi >> (sb - 32)) & 0xFFu;
                below = __popc(mlo) + __popc(mhi & ((1u << (sb - 32)) - 1u));
            }
            int pos = ep + below;
            while (byte) {
                int bt = __builtin_ctz(byte);
                byte &= byte - 1;
                list[pos++] = (unsigned short)(lane * 8 + bt);  // j = lane*8 + bt
            }
        }

        // xp prefetch AFTER poll: its latency hides under the gather and never
        // enters the poll's wait set.
        float xp_next = base[(size_t)(t < 1023 ? t + 1 : 1023) * 512];

        float recA = 0.0f, recB = 0.0f;
        if (k > 0) {
            int nch = (k + 7) >> 3;
            C8 b0, b1;
            b0 = fetch8_lds(list, 0, wrs, lane);
            if (nch > 1) b1 = fetch8_lds(list, 1, wrs, lane);
            int cc = 0;
            for (; cc + 4 <= nch; cc += 2) {
                consume8(b0, (cc + 0) * 8, kA, k, recA, recB);
                b0 = fetch8_lds(list, cc + 2, wrs, lane);
                consume8(b1, (cc + 1) * 8, kA, k, recA, recB);
                b1 = fetch8_lds(list, cc + 3, wrs, lane);
            }
            int rem = nch - cc;   // 1..3
            if (rem >= 1) consume8(b0, (cc + 0) * 8, kA, k, recA, recB);
            if (rem >= 3) b0 = fetch8_lds(list, cc + 2, wrs, lane);
            if (rem >= 2) consume8(b1, (cc + 1) * 8, kA, k, recA, recB);
            if (rem >= 3) consume8(b0, (cc + 2) * 8, kA, k, recA, recB);
        }

        // state update (FROZEN semantics)
        float rec = recA + recB;        // kc-block join
        float cur = xp + rec;
        float tmp = ALPHA_F * hstate;
        asm volatile("" : "+v"(tmp));   // forbid fma contraction
        float hn = tmp + cur;
        bool sp = (hn >= 1.0f);
        hstate = sp ? 0.0f : hn;

        // publish own 64-bit mask FIRST (single 16B device-coherent store)
        unsigned long long bm = __ballot(sp);
        if (lane == 0) {
            u32x4 pk;
            pk.x = (unsigned)bm; pk.y = (unsigned)(bm >> 32);
            pk.z = (unsigned)(t + 1); pk.w = 0u;
            u32x4* qp = syn + (((t & 1) * 64 + s) * 8) + c;
            asm volatile("global_store_dwordx4 %0, %1, off sc0 sc1"
                         :: "v"(qp), "v"(pk) : "memory");
        }

        base[(size_t)t * 512] = sp ? 1.0f : 0.0f;
        cnt += sp ? 1 : 0;
        xp = xp_next;
    }

    // retire the final stray probe BEFORE its registers can be reused, and
    // keep prb0/prb1 alive up to this point.
    asm volatile("s_waitcnt vmcnt(0)" ::: "memory");
    asm volatile("" :: "v"(prb0), "v"(prb1));

    g_mean[s * 512 + n] = (float)cnt * (1.0f / 1024.0f);
}

// ---------------------------------------------------------------------------
// Kernel C: readout -- UNCHANGED.
// ---------------------------------------------------------------------------
__global__ __launch_bounds__(64) void readout_kernel(
    const float* __restrict__ Wo, const float* __restrict__ bo,
    float* __restrict__ out)
{
    const int b = blockIdx.x, o = blockIdx.y;
    const int lane = threadIdx.x;
    const float* mr = g_mean + b * 512;
    const float* wr = Wo + o * 512;
    double s = 0.0;
    for (int i = lane; i < 512; i += 64) s += (double)mr[i] * (double)wr[i];
    #pragma unroll
    for (int off = 32; off; off >>= 1) s += __shfl_down(s, off);
    if (lane == 0) out[b * 10 + o] = (float)(s + (double)bo[o]);
}

extern "C" void kernel_launch(void* const* d_in, const int* in_sizes, int n_in,
                              void* d_out, int out_size, void* d_ws, size_t ws_size,
                              hipStream_t stream) {
    const float* x  = (const float*)d_in[0];
    const float* Wi = (const float*)d_in[1];
    const float* bi = (const float*)d_in[2];
    const float* Wr = (const float*)d_in[3];
    const float* Wo = (const float*)d_in[4];
    const float* bo = (const float*)d_in[5];

    float* out = (float*)d_out;
    float* hid = out + 640;  // hidden_states region doubles as x_proj scratch

    // zero the mask-exchange records (2 slots x 64 samples x 8 slices x 16B)
    (void)hipMemsetAsync(d_ws, 0, 2 * 64 * 8 * 16, stream);

    dim3 gA(1024, 16);
    xproj_kernel<<<gA, 256, 0, stream>>>(x, Wi, bi, hid);

    scan_kernel<<<256, 128, 0, stream>>>(Wr, hid, (u32x4*)d_ws);

    dim3 gC(64, 10);
    readout_kernel<<<gC, 64, 0, stream>>>(Wo, bo, out);
}